// Round 8
// baseline (93.466 us; speedup 1.0000x reference)
//
#include <hip/hip_runtime.h>

// out[b,k,h,w] = w[k,0]*side5 + w[k,1]*side4 + w[k,2]*side1 + w[k,3]*side2
//              + w[k,4]*side3 + bias[k]
// B=8, K=19, H=W=512.
// R6's explicit one-k-ahead software pipeline, now with __launch_bounds__
// (256, 4): raises the VGPR cap from 64 (8-wave default) to 128 so the
// ~80 live VGPRs of the pipeline survive regalloc instead of being sunk
// (R6 failure mode: VGPR stayed 32 -> no overlap). 1024 blocks = exactly
// 4 waves/EU residency. nt stores kept; nt loads dropped (proven null).

#define KK   19
#define HW4  65536      // (512*512)/4 float4s per plane

typedef float f32x4 __attribute__((ext_vector_type(4)));

__global__ __launch_bounds__(256, 4) void grouped_conv_fuse_kernel(
    const float* __restrict__ s1, const float* __restrict__ s2,
    const float* __restrict__ s3, const float* __restrict__ s4,
    const float* __restrict__ s5, const float* __restrict__ w,
    const float* __restrict__ bias, float* __restrict__ out)
{
    const f32x4* __restrict__ v1 = (const f32x4*)s1;
    const f32x4* __restrict__ v2 = (const f32x4*)s2;
    const f32x4* __restrict__ v3 = (const f32x4*)s3;
    const f32x4* __restrict__ v4 = (const f32x4*)s4;
    const f32x4* __restrict__ v5 = (const f32x4*)s5;
    f32x4* __restrict__ vo = (f32x4*)out;

    // 1024 blocks: 128 blocks per batch, each block covers 512 float4 slots
    int b   = blockIdx.x >> 7;                            // 0..7
    int sp0 = ((blockIdx.x & 127) << 9) + threadIdx.x;    // first slot
    int si0 = (b << 16) + sp0;
    int si1 = si0 + 256;

    f32x4 p1 = v1[si0], q1 = v1[si1];
    f32x4 p2 = v2[si0], q2 = v2[si1];
    f32x4 p3 = v3[si0], q3 = v3[si1];

    long base0 = (long)b * KK * HW4 + sp0;
    long base1 = base0 + 256;

    // prologue: load k=0
    f32x4 x5a = v5[base0], x5b = v5[base1];
    f32x4 x4a = v4[base0], x4b = v4[base1];

    for (int k = 0; k < KK - 1; ++k) {
        long n0 = base0 + (long)(k + 1) * HW4;
        long n1 = base1 + (long)(k + 1) * HW4;
        // issue k+1 loads FIRST -> in flight during k's compute+store
        f32x4 y5a = v5[n0], y5b = v5[n1];
        f32x4 y4a = v4[n0], y4b = v4[n1];

        float w0 = w[k * 5 + 0], w1 = w[k * 5 + 1], w2 = w[k * 5 + 2];
        float w3 = w[k * 5 + 3], w4 = w[k * 5 + 4], bb = bias[k];

        long i0 = base0 + (long)k * HW4;
        long i1 = base1 + (long)k * HW4;
        f32x4 oa = w0 * x5a + w1 * x4a + w2 * p1 + w3 * p2 + w4 * p3 + bb;
        f32x4 ob = w0 * x5b + w1 * x4b + w2 * q1 + w3 * q2 + w4 * q3 + bb;
        __builtin_nontemporal_store(oa, &vo[i0]);
        __builtin_nontemporal_store(ob, &vo[i1]);

        x5a = y5a; x5b = y5b; x4a = y4a; x4b = y4b;
    }

    // epilogue: k = KK-1
    {
        const int k = KK - 1;
        float w0 = w[k * 5 + 0], w1 = w[k * 5 + 1], w2 = w[k * 5 + 2];
        float w3 = w[k * 5 + 3], w4 = w[k * 5 + 4], bb = bias[k];
        long i0 = base0 + (long)k * HW4;
        long i1 = base1 + (long)k * HW4;
        f32x4 oa = w0 * x5a + w1 * x4a + w2 * p1 + w3 * p2 + w4 * p3 + bb;
        f32x4 ob = w0 * x5b + w1 * x4b + w2 * q1 + w3 * q2 + w4 * q3 + bb;
        __builtin_nontemporal_store(oa, &vo[i0]);
        __builtin_nontemporal_store(ob, &vo[i1]);
    }
}

extern "C" void kernel_launch(void* const* d_in, const int* in_sizes, int n_in,
                              void* d_out, int out_size, void* d_ws, size_t ws_size,
                              hipStream_t stream) {
    const float* s1   = (const float*)d_in[0];
    const float* s2   = (const float*)d_in[1];
    const float* s3   = (const float*)d_in[2];
    const float* s4   = (const float*)d_in[3];
    const float* s5   = (const float*)d_in[4];
    const float* w    = (const float*)d_in[5];
    const float* bias = (const float*)d_in[6];
    float* out        = (float*)d_out;

    grouped_conv_fuse_kernel<<<1024, 256, 0, stream>>>(s1, s2, s3, s4, s5, w, bias, out);
}

// Round 9
// 76.940 us; speedup vs baseline: 1.2148x; 1.2148x over previous
//
#include <hip/hip_runtime.h>

// out[b,k,h,w] = w[k,0]*side5 + w[k,1]*side4 + w[k,2]*side1 + w[k,3]*side2
//              + w[k,4]*side3 + bias[k]
// B=8, K=19, H=W=512.
// EXACT R5 structure (best: 78.6 us) + FULL k-loop unroll. R6/R8 proved
// explicit prefetch rotation gets sunk by the scheduler (VGPR stuck at 32);
// straight-line code lets it hoist loads on its own terms instead.
// nt stores kept; nt loads on k>=14 kept (R5 mix, unchanged for clean A/B).

#define KK   19
#define HW4  65536      // (512*512)/4 float4s per plane
#define KRES 14

typedef float f32x4 __attribute__((ext_vector_type(4)));

__global__ __launch_bounds__(256, 4) void grouped_conv_fuse_kernel(
    const float* __restrict__ s1, const float* __restrict__ s2,
    const float* __restrict__ s3, const float* __restrict__ s4,
    const float* __restrict__ s5, const float* __restrict__ w,
    const float* __restrict__ bias, float* __restrict__ out)
{
    const f32x4* __restrict__ v1 = (const f32x4*)s1;
    const f32x4* __restrict__ v2 = (const f32x4*)s2;
    const f32x4* __restrict__ v3 = (const f32x4*)s3;
    const f32x4* __restrict__ v4 = (const f32x4*)s4;
    const f32x4* __restrict__ v5 = (const f32x4*)s5;
    f32x4* __restrict__ vo = (f32x4*)out;

    // 1024 blocks: 128 blocks per batch, each block covers 512 float4 slots
    int b   = blockIdx.x >> 7;                            // 0..7
    int sp0 = ((blockIdx.x & 127) << 9) + threadIdx.x;    // first slot
    int si0 = (b << 16) + sp0;
    int si1 = si0 + 256;

    f32x4 p1 = v1[si0], q1 = v1[si1];
    f32x4 p2 = v2[si0], q2 = v2[si1];
    f32x4 p3 = v3[si0], q3 = v3[si1];

    long base0 = (long)b * KK * HW4 + sp0;
    long base1 = base0 + 256;

    // ---- resident ks: normal loads ----
    #pragma unroll
    for (int k = 0; k < KRES; ++k) {
        long i0 = base0 + (long)k * HW4;
        long i1 = base1 + (long)k * HW4;
        f32x4 x5a = v5[i0], x5b = v5[i1];
        f32x4 x4a = v4[i0], x4b = v4[i1];

        float w0 = w[k * 5 + 0], w1 = w[k * 5 + 1], w2 = w[k * 5 + 2];
        float w3 = w[k * 5 + 3], w4 = w[k * 5 + 4], bb = bias[k];

        f32x4 oa = w0 * x5a + w1 * x4a + w2 * p1 + w3 * p2 + w4 * p3 + bb;
        f32x4 ob = w0 * x5b + w1 * x4b + w2 * q1 + w3 * q2 + w4 * q3 + bb;
        __builtin_nontemporal_store(oa, &vo[i0]);
        __builtin_nontemporal_store(ob, &vo[i1]);
    }

    // ---- streamed ks: non-temporal loads ----
    #pragma unroll
    for (int k = KRES; k < KK; ++k) {
        long i0 = base0 + (long)k * HW4;
        long i1 = base1 + (long)k * HW4;
        f32x4 x5a = __builtin_nontemporal_load(&v5[i0]);
        f32x4 x5b = __builtin_nontemporal_load(&v5[i1]);
        f32x4 x4a = __builtin_nontemporal_load(&v4[i0]);
        f32x4 x4b = __builtin_nontemporal_load(&v4[i1]);

        float w0 = w[k * 5 + 0], w1 = w[k * 5 + 1], w2 = w[k * 5 + 2];
        float w3 = w[k * 5 + 3], w4 = w[k * 5 + 4], bb = bias[k];

        f32x4 oa = w0 * x5a + w1 * x4a + w2 * p1 + w3 * p2 + w4 * p3 + bb;
        f32x4 ob = w0 * x5b + w1 * x4b + w2 * q1 + w3 * q2 + w4 * q3 + bb;
        __builtin_nontemporal_store(oa, &vo[i0]);
        __builtin_nontemporal_store(ob, &vo[i1]);
    }
}

extern "C" void kernel_launch(void* const* d_in, const int* in_sizes, int n_in,
                              void* d_out, int out_size, void* d_ws, size_t ws_size,
                              hipStream_t stream) {
    const float* s1   = (const float*)d_in[0];
    const float* s2   = (const float*)d_in[1];
    const float* s3   = (const float*)d_in[2];
    const float* s4   = (const float*)d_in[3];
    const float* s5   = (const float*)d_in[4];
    const float* w    = (const float*)d_in[5];
    const float* bias = (const float*)d_in[6];
    float* out        = (float*)d_out;

    grouped_conv_fuse_kernel<<<1024, 256, 0, stream>>>(s1, s2, s3, s4, s5, w, bias, out);
}